// Round 9
// baseline (143.372 us; speedup 1.0000x reference)
//
#include <hip/hip_runtime.h>
#include <math.h>

#define BATCH 4
#define SEQT  4096
#define CDIM  512
#define HDIM  64

typedef unsigned short ushort_t;
typedef __attribute__((ext_vector_type(8))) short bf16x8;
typedef __attribute__((ext_vector_type(4))) float f32x4;

#define MFMA16(a, b, c) __builtin_amdgcn_mfma_f32_16x16x32_bf16((a), (b), (c), 0, 0, 0)
#define NEG (-1e30f)

__device__ __forceinline__ ushort_t f2bf(float f) {
  union { float f; unsigned int u; } v;
  v.f = f;
  unsigned int u = v.u;
  u += 0x7fffu + ((u >> 16) & 1u);  // round-to-nearest-even
  return (ushort_t)(u >> 16);
}
__device__ __forceinline__ unsigned int pk2(float a, float b) {
  return (unsigned int)f2bf(a) | ((unsigned int)f2bf(b) << 16);
}

// ---------------------------------------------------------------------------
// Kernel 0: W[c][h] fp32 -> wtf in MFMA B-fragment order (unchanged).
// ---------------------------------------------------------------------------
__global__ __launch_bounds__(256) void convert_w(
    const float* __restrict__ Wq, const float* __restrict__ Wk,
    const float* __restrict__ Wv, ushort_t* __restrict__ wtf) {
  int g = blockIdx.x * 256 + threadIdx.x;  // 0 .. 12287
  int lane = g & 63;
  int nt = (g >> 6) & 3;
  int ks = (g >> 8) & 15;
  int mat = g >> 12;
  const float* W = (mat == 0) ? Wq : (mat == 1) ? Wk : Wv;
  const float sc = (mat == 0) ? 0.04419417382415922f : 1.0f;  // 1/sqrt(512)
  int n = lane & 15, quad = lane >> 4;
  int h = nt * 16 + n;
  int c0 = ks * 32 + quad * 8;
  ushort_t tmp[8];
#pragma unroll
  for (int j = 0; j < 8; ++j) tmp[j] = f2bf(W[(c0 + j) * HDIM + h] * sc);
  *(bf16x8*)(wtf + (size_t)g * 8) = *(const bf16x8*)tmp;
}

// ---------------------------------------------------------------------------
// Kernel 1: QKV projection, K-split, XOR-swizzled LDS (unchanged from r8).
// ---------------------------------------------------------------------------
__global__ __launch_bounds__(384) void qkv_proj(
    const float* __restrict__ x, const ushort_t* __restrict__ wtf,
    ushort_t* __restrict__ qbf, ushort_t* __restrict__ kbf,
    ushort_t* __restrict__ vbf) {
  __shared__ ushort_t Xs[16 * 512];     // 16 KB, swizzled
  __shared__ float Facc[3 * 1088];      // 12.75 KB (stride 17/lane)
  __shared__ ushort_t Pk[3][16 * 64];   // 6 KB, swizzled

  const int tid = threadIdx.x;
  const int row0 = blockIdx.x * 16;  // global row = b*4096 + t

  const float4* xg = (const float4*)(x + (size_t)row0 * CDIM);
  for (int i = tid; i < 16 * (CDIM / 4); i += 384) {
    float4 xv = xg[i];
    int r = i >> 7, c4 = i & 127;
    int chunk = (c4 >> 1) ^ (r & 7);  // 16B chunk swizzle
    uint2 u;
    u.x = pk2(xv.x, xv.y);
    u.y = pk2(xv.z, xv.w);
    *(uint2*)&Xs[r * 512 + chunk * 8 + (c4 & 1) * 4] = u;
  }
  __syncthreads();

  const int lane = tid & 63;
  const int w = tid >> 6;   // 0..5
  const int mat = w >> 1;   // 0=q 1=k 2=v
  const int kh = w & 1;     // k-half
  const int n = lane & 15, quad = lane >> 4;
  const ushort_t* wb = wtf + mat * 32768;

  f32x4 acc[4];
#pragma unroll
  for (int nt = 0; nt < 4; ++nt) acc[nt] = (f32x4){0.f, 0.f, 0.f, 0.f};

  bf16x8 bcur[4];
#pragma unroll
  for (int nt = 0; nt < 4; ++nt)
    bcur[nt] = *(const bf16x8*)&wb[(kh * 8 * 4 + nt) * 512 + lane * 8];

  for (int kk = 0; kk < 8; ++kk) {
    const int ks = kh * 8 + kk;
    bf16x8 a = *(const bf16x8*)&Xs[n * 512 + ((4 * ks + quad) ^ (n & 7)) * 8];
    bf16x8 bnext[4];
    if (kk < 7) {
#pragma unroll
      for (int nt = 0; nt < 4; ++nt)
        bnext[nt] = *(const bf16x8*)&wb[((ks + 1) * 4 + nt) * 512 + lane * 8];
    }
#pragma unroll
    for (int nt = 0; nt < 4; ++nt) acc[nt] = MFMA16(a, bcur[nt], acc[nt]);
    if (kk < 7) {
#pragma unroll
      for (int nt = 0; nt < 4; ++nt) bcur[nt] = bnext[nt];
    }
  }

  if (kh == 1) {
#pragma unroll
    for (int nt = 0; nt < 4; ++nt)
#pragma unroll
      for (int i = 0; i < 4; ++i)
        Facc[mat * 1088 + lane * 17 + nt * 4 + i] = acc[nt][i];
  }
  __syncthreads();

  if (kh == 0) {
#pragma unroll
    for (int nt = 0; nt < 4; ++nt)
#pragma unroll
      for (int i = 0; i < 4; ++i) {
        acc[nt][i] += Facc[mat * 1088 + lane * 17 + nt * 4 + i];
        const int row = quad * 4 + i;
        Pk[mat][row * 64 + (((2 * nt + (n >> 3)) ^ (row & 7)) * 8) + (n & 7)] =
            f2bf(acc[nt][i]);
      }
    if (mat < 2) {
      ushort_t* dst = (mat == 0) ? qbf : kbf;
#pragma unroll
      for (int ks2 = 0; ks2 < 2; ++ks2) {
        bf16x8 fr = *(const bf16x8*)&Pk[mat][n * 64 +
                                            (((4 * ks2 + quad) ^ (n & 7)) * 8)];
        *(bf16x8*)(dst + (size_t)((row0 >> 4) * 2 + ks2) * 512 + lane * 8) = fr;
      }
    } else {
      const int b = row0 >> 12, t0 = row0 & 4095;
      const int kt = t0 >> 6, kslot = (t0 >> 5) & 1, tsub = (t0 >> 4) & 1;
      if ((quad >> 1) == tsub) {
        const int lq = quad & 1;
#pragma unroll
        for (int nt = 0; nt < 4; ++nt) {
          ushort_t tmp[8];
#pragma unroll
          for (int j = 0; j < 8; ++j) {
            const int row = lq * 8 + j;
            tmp[j] = Pk[2][row * 64 +
                           (((2 * nt + (n >> 3)) ^ (row & 7)) * 8) + (n & 7)];
          }
          *(bf16x8*)(vbf + (size_t)(((b * 64 + kt) * 4 + nt) * 2 + kslot) * 512 +
                     lane * 8) = *(const bf16x8*)tmp;
        }
      }
    }
  }
}

// ---------------------------------------------------------------------------
// Kernel 2: causal flash attention. Each wave owns ALL 32 q-rows of its tile
// and strides kt by 8: the same K/V fragment loads feed 2x the MFMAs
// (vs r8's 16-row waves), halving load-latency exposure per unit work.
// l accumulated as lane-local fp32 partials (no ones-MFMA), reduced once
// after the k-loop. Max-free softmax; XOR-swizzled P round-trip; no k-loop
// barriers; additive 8-wave merge. Peak live ~102 VGPR (cap 128, no spill).
// Grid 512 = 4 b x 128 q-tiles (heavy-first); block 512 = 8 waves.
// ---------------------------------------------------------------------------
__global__ __launch_bounds__(512, 4) void attn(
    const ushort_t* __restrict__ qbf, const ushort_t* __restrict__ kbf,
    const ushort_t* __restrict__ vbf, float* __restrict__ out) {
  // Union: Ps [8][32*64] shorts (32 KB) in k-loop;
  //        Om [8][32*68] floats (69632 B) + Ol [8][32] floats at merge.
  __shared__ __align__(16) char smem[70656];
  ushort_t* Ps = (ushort_t*)smem;
  float* Om = (float*)smem;
  float* Ol = (float*)(smem + 69632);

  const int tid = threadIdx.x;
  const int lane = tid & 63;
  const int w = tid >> 6;  // 0..7 (= kt0, stride 8)
  const int n = lane & 15, quad = lane >> 4;

  const int b = blockIdx.x & 3;
  const int qt = 127 - (blockIdx.x >> 2);  // heavy-first
  const int q0 = qt * 32;

  const ushort_t* qB = qbf + (size_t)b * 512 * 512;
  const ushort_t* kB = kbf + (size_t)b * 512 * 512;
  const ushort_t* vB = vbf + (size_t)b * 512 * 512;
  float* oB = out + (size_t)b * SEQT * HDIM;

  // Q A-fragments for both 16-row halves: group = qt*2 + m2.
  bf16x8 qf[2][2];
#pragma unroll
  for (int m2 = 0; m2 < 2; ++m2)
#pragma unroll
    for (int ks = 0; ks < 2; ++ks)
      qf[m2][ks] = *(const bf16x8*)&qB[(size_t)((qt * 2 + m2) * 2 + ks) * 512 +
                                       lane * 8];

  f32x4 o[2][4];
  float lsum[2][4];
#pragma unroll
  for (int m2 = 0; m2 < 2; ++m2)
#pragma unroll
    for (int nt = 0; nt < 4; ++nt) o[m2][nt] = (f32x4){0.f, 0.f, 0.f, 0.f};
#pragma unroll
  for (int m2 = 0; m2 < 2; ++m2)
#pragma unroll
    for (int i = 0; i < 4; ++i) lsum[m2][i] = 0.f;

  const int ktiles = (q0 + 95) >> 6;  // ceil((q0+32)/64)
  ushort_t* Pw = Ps + w * 2048;       // 32 rows x 64 shorts, swizzled

  for (int kt = w; kt < ktiles; kt += 8) {
    const int k0 = kt * 64;

    // S = Q K^T : 16 MFMAs from 8 kf loads (each kf feeds both row halves).
    f32x4 s[2][4];
#pragma unroll
    for (int m2 = 0; m2 < 2; ++m2)
#pragma unroll
      for (int nt = 0; nt < 4; ++nt) s[m2][nt] = (f32x4){0.f, 0.f, 0.f, 0.f};
#pragma unroll
    for (int ks = 0; ks < 2; ++ks)
#pragma unroll
      for (int nt = 0; nt < 4; ++nt) {
        bf16x8 kf = *(const bf16x8*)&kB[(size_t)((kt * 4 + nt) * 2 + ks) * 512 +
                                        lane * 8];
        s[0][nt] = MFMA16(qf[0][ks], kf, s[0][nt]);
        s[1][nt] = MFMA16(qf[1][ks], kf, s[1][nt]);
      }

    // Causal mask (diagonal tiles only).
    if (k0 + 63 > q0) {
#pragma unroll
      for (int m2 = 0; m2 < 2; ++m2) {
        const int rbase = q0 + m2 * 16 + quad * 4;
#pragma unroll
        for (int nt = 0; nt < 4; ++nt) {
          const int col = k0 + nt * 16 + n;
#pragma unroll
          for (int i = 0; i < 4; ++i)
            if (col > rbase + i) s[m2][nt][i] = NEG;
        }
      }
    }

    // Max-free softmax: p = exp(s); lane-local l partials; swizzled P pack.
#pragma unroll
    for (int m2 = 0; m2 < 2; ++m2)
#pragma unroll
      for (int nt = 0; nt < 4; ++nt)
#pragma unroll
        for (int i = 0; i < 4; ++i) {
          const float p = __expf(s[m2][nt][i]);
          lsum[m2][i] += p;
          const int row = m2 * 16 + quad * 4 + i;
          Pw[row * 64 + (((2 * nt + (n >> 3)) ^ (row & 7)) * 8) + (n & 7)] =
              f2bf(p);
        }

    // P A-frags back (conflict-free b128); O += P V (vf feeds both halves).
    bf16x8 pa[2][2];
#pragma unroll
    for (int m2 = 0; m2 < 2; ++m2)
#pragma unroll
      for (int ks = 0; ks < 2; ++ks)
        pa[m2][ks] = *(const bf16x8*)&Pw[(m2 * 16 + n) * 64 +
                                         (((4 * ks + quad) ^ (n & 7)) * 8)];
#pragma unroll
    for (int ks = 0; ks < 2; ++ks)
#pragma unroll
      for (int nt = 0; nt < 4; ++nt) {
        bf16x8 vf = *(const bf16x8*)&vB[(size_t)((kt * 4 + nt) * 2 + ks) * 512 +
                                        lane * 8];
        o[0][nt] = MFMA16(pa[0][ks], vf, o[0][nt]);
        o[1][nt] = MFMA16(pa[1][ks], vf, o[1][nt]);
      }
  }

  // Reduce lsum across the 16 n-lanes of each row (once, after the k-loop).
#pragma unroll
  for (int off = 1; off < 16; off <<= 1)
#pragma unroll
    for (int m2 = 0; m2 < 2; ++m2)
#pragma unroll
      for (int i = 0; i < 4; ++i)
        lsum[m2][i] += __shfl_xor(lsum[m2][i], off);

  // ---- Additive merge of 8 waves. ----
  __syncthreads();  // all waves done with Ps (aliases Om)

  float* OmW = Om + w * 2176;  // 32 rows x 68 floats
#pragma unroll
  for (int m2 = 0; m2 < 2; ++m2)
#pragma unroll
    for (int nt = 0; nt < 4; ++nt)
#pragma unroll
      for (int i = 0; i < 4; ++i)
        OmW[(m2 * 16 + quad * 4 + i) * 68 + nt * 16 + n] = o[m2][nt][i];
  if (n == 0)
#pragma unroll
    for (int m2 = 0; m2 < 2; ++m2)
#pragma unroll
      for (int i = 0; i < 4; ++i)
        Ol[w * 32 + m2 * 16 + quad * 4 + i] = lsum[m2][i];
  __syncthreads();

  // Final combine: 512 threads x 4 floats.
  {
    const int r = tid >> 4;          // 0..31
    const int c0 = (tid & 15) * 4;   // 0..60
    float ax = 0.f, ay = 0.f, az = 0.f, aw = 0.f, ls = 0.f;
#pragma unroll
    for (int ww = 0; ww < 8; ++ww) {
      const float4 vv = *(const float4*)&Om[ww * 2176 + r * 68 + c0];
      ax += vv.x; ay += vv.y; az += vv.z; aw += vv.w;
      ls += Ol[ww * 32 + r];
    }
    const float inv = 1.0f / ls;
    *(float4*)&oB[(size_t)(q0 + r) * HDIM + c0] =
        make_float4(ax * inv, ay * inv, az * inv, aw * inv);
  }
}

extern "C" void kernel_launch(void* const* d_in, const int* in_sizes, int n_in,
                              void* d_out, int out_size, void* d_ws, size_t ws_size,
                              hipStream_t stream) {
  const float* x = (const float*)d_in[0];
  const float* Wq = (const float*)d_in[1];
  const float* Wk = (const float*)d_in[2];
  const float* Wv = (const float*)d_in[3];
  float* out = (float*)d_out;

  ushort_t* wtf = (ushort_t*)d_ws;
  ushort_t* qbf = wtf + 3 * 16 * 4 * 512;
  ushort_t* kbf = qbf + (size_t)BATCH * 512 * 512;
  ushort_t* vbf = kbf + (size_t)BATCH * 512 * 512;

  convert_w<<<48, 256, 0, stream>>>(Wq, Wk, Wv, wtf);
  qkv_proj<<<BATCH * SEQT / 16, 384, 0, stream>>>(x, wtf, qbf, kbf, vbf);
  attn<<<512, 512, 0, stream>>>(qbf, kbf, vbf, out);
}

// Round 10
// 119.702 us; speedup vs baseline: 1.1977x; 1.1977x over previous
//
#include <hip/hip_runtime.h>
#include <math.h>

#define BATCH 4
#define SEQT  4096
#define CDIM  512
#define HDIM  64

typedef unsigned short ushort_t;
typedef __attribute__((ext_vector_type(8))) short bf16x8;
typedef __attribute__((ext_vector_type(4))) float f32x4;

#define MFMA16(a, b, c) __builtin_amdgcn_mfma_f32_16x16x32_bf16((a), (b), (c), 0, 0, 0)
#define NEG (-1e30f)

__device__ __forceinline__ ushort_t f2bf(float f) {
  union { float f; unsigned int u; } v;
  v.f = f;
  unsigned int u = v.u;
  u += 0x7fffu + ((u >> 16) & 1u);  // round-to-nearest-even
  return (ushort_t)(u >> 16);
}
__device__ __forceinline__ unsigned int pk2(float a, float b) {
  return (unsigned int)f2bf(a) | ((unsigned int)f2bf(b) << 16);
}

// ---------------------------------------------------------------------------
// Kernel 0: W[c][h] fp32 -> wtf in MFMA B-fragment order.
// ---------------------------------------------------------------------------
__global__ __launch_bounds__(256) void convert_w(
    const float* __restrict__ Wq, const float* __restrict__ Wk,
    const float* __restrict__ Wv, ushort_t* __restrict__ wtf) {
  int g = blockIdx.x * 256 + threadIdx.x;  // 0 .. 12287
  int lane = g & 63;
  int nt = (g >> 6) & 3;
  int ks = (g >> 8) & 15;
  int mat = g >> 12;
  const float* W = (mat == 0) ? Wq : (mat == 1) ? Wk : Wv;
  const float sc = (mat == 0) ? 0.04419417382415922f : 1.0f;  // 1/sqrt(512)
  int n = lane & 15, quad = lane >> 4;
  int h = nt * 16 + n;
  int c0 = ks * 32 + quad * 8;
  ushort_t tmp[8];
#pragma unroll
  for (int j = 0; j < 8; ++j) tmp[j] = f2bf(W[(c0 + j) * HDIM + h] * sc);
  *(bf16x8*)(wtf + (size_t)g * 8) = *(const bf16x8*)tmp;
}

// ---------------------------------------------------------------------------
// Kernel 1: QKV projection — round-6 version (best measured: ~29 us incl
// convert). 16 rows/block, 1024 blocks, 384 threads = 6 waves (mat, k-half),
// double-buffered B-frag loads, fp32 LDS merge of k-halves.
// Outputs in MFMA fragment order: qbf (A-frags), kbf (B-frags), vbf (V^T).
// ---------------------------------------------------------------------------
#define XP 520  // shorts

__global__ __launch_bounds__(384) void qkv_proj(
    const float* __restrict__ x, const ushort_t* __restrict__ wtf,
    ushort_t* __restrict__ qbf, ushort_t* __restrict__ kbf,
    ushort_t* __restrict__ vbf) {
  __shared__ ushort_t Xs[16 * XP];      // 16.6 KB
  __shared__ float Facc[3 * 1088];      // 12.75 KB (stride 17/lane)
  __shared__ ushort_t Pk[3][16 * 72];   // 6.75 KB

  const int tid = threadIdx.x;
  const int row0 = blockIdx.x * 16;  // global row = b*4096 + t

  const float4* xg = (const float4*)(x + (size_t)row0 * CDIM);
  for (int i = tid; i < 16 * (CDIM / 4); i += 384) {
    float4 xv = xg[i];
    int r = i >> 7, c4 = i & 127;
    uint2 u;
    u.x = pk2(xv.x, xv.y);
    u.y = pk2(xv.z, xv.w);
    *(uint2*)&Xs[r * XP + c4 * 4] = u;
  }
  __syncthreads();

  const int lane = tid & 63;
  const int w = tid >> 6;   // 0..5
  const int mat = w >> 1;   // 0=q 1=k 2=v
  const int kh = w & 1;     // k-half: ks in [kh*8, kh*8+8)
  const int n = lane & 15, quad = lane >> 4;
  const ushort_t* wb = wtf + mat * 32768;

  f32x4 acc[4];
#pragma unroll
  for (int nt = 0; nt < 4; ++nt) acc[nt] = (f32x4){0.f, 0.f, 0.f, 0.f};

  bf16x8 bcur[4];
#pragma unroll
  for (int nt = 0; nt < 4; ++nt)
    bcur[nt] = *(const bf16x8*)&wb[(kh * 8 * 4 + nt) * 512 + lane * 8];

  for (int kk = 0; kk < 8; ++kk) {
    const int ks = kh * 8 + kk;
    bf16x8 a = *(const bf16x8*)&Xs[n * XP + ks * 32 + quad * 8];
    bf16x8 bnext[4];
    if (kk < 7) {
#pragma unroll
      for (int nt = 0; nt < 4; ++nt)
        bnext[nt] = *(const bf16x8*)&wb[((ks + 1) * 4 + nt) * 512 + lane * 8];
    }
#pragma unroll
    for (int nt = 0; nt < 4; ++nt) acc[nt] = MFMA16(a, bcur[nt], acc[nt]);
    if (kk < 7) {
#pragma unroll
      for (int nt = 0; nt < 4; ++nt) bcur[nt] = bnext[nt];
    }
  }

  // Merge k-halves: kh=1 writes partials, kh=0 accumulates.
  if (kh == 1) {
#pragma unroll
    for (int nt = 0; nt < 4; ++nt)
#pragma unroll
      for (int i = 0; i < 4; ++i)
        Facc[mat * 1088 + lane * 17 + nt * 4 + i] = acc[nt][i];
  }
  __syncthreads();

  if (kh == 0) {
#pragma unroll
    for (int nt = 0; nt < 4; ++nt)
#pragma unroll
      for (int i = 0; i < 4; ++i) {
        acc[nt][i] += Facc[mat * 1088 + lane * 17 + nt * 4 + i];
        Pk[mat][(quad * 4 + i) * 72 + nt * 16 + n] = f2bf(acc[nt][i]);
      }
    if (mat < 2) {
      ushort_t* dst = (mat == 0) ? qbf : kbf;
#pragma unroll
      for (int ks2 = 0; ks2 < 2; ++ks2) {
        bf16x8 fr =
            *(const bf16x8*)&Pk[mat][n * 72 + ks2 * 32 + quad * 8];
        *(bf16x8*)(dst + (size_t)((row0 >> 4) * 2 + ks2) * 512 + lane * 8) = fr;
      }
    } else {
      const int b = row0 >> 12, t0 = row0 & 4095;
      const int kt = t0 >> 6, kslot = (t0 >> 5) & 1, tsub = (t0 >> 4) & 1;
      if ((quad >> 1) == tsub) {
        const int lq = quad & 1;
#pragma unroll
        for (int nt = 0; nt < 4; ++nt) {
          ushort_t tmp[8];
#pragma unroll
          for (int j = 0; j < 8; ++j)
            tmp[j] = Pk[2][(lq * 8 + j) * 72 + nt * 16 + n];
          *(bf16x8*)(vbf + (size_t)(((b * 64 + kt) * 4 + nt) * 2 + kslot) * 512 +
                     lane * 8) = *(const bf16x8*)tmp;
        }
      }
    }
  }
}

// ---------------------------------------------------------------------------
// Kernel 2: causal flash attention, UNIFORM paired blocks.
// BR=16: 256 q-tiles/batch. Block (b, j) processes q-tiles 255-j then j:
// combined k-work ~66 tiles for every block -> no tail imbalance.
// 8 waves; wave owns all 16 rows, kt stride 8. Live set ~85 VGPR (no spill
// at (512,4) — r7/r9 lesson: stay under ~100). Max-free softmax; swizzled
// P round-trip; lane-local l partials; additive 8-wave merge per tile.
// ---------------------------------------------------------------------------
__global__ __launch_bounds__(512, 4) void attn(
    const ushort_t* __restrict__ qbf, const ushort_t* __restrict__ kbf,
    const ushort_t* __restrict__ vbf, float* __restrict__ out) {
  // Union: Ps [8][16*64] shorts (16 KB) in k-loop;
  //        Om [8][16*68] floats (34816 B) + Ol [8][16] at merge.
  __shared__ __align__(16) char smem[35328];
  ushort_t* Ps = (ushort_t*)smem;
  float* Om = (float*)smem;
  float* Ol = (float*)(smem + 34816);

  const int tid = threadIdx.x;
  const int lane = tid & 63;
  const int w = tid >> 6;  // 0..7 (= kt0, stride 8)
  const int n = lane & 15, quad = lane >> 4;

  const int b = blockIdx.x & 3;
  const int j = blockIdx.x >> 2;  // 0..127

  const ushort_t* qB = qbf + (size_t)b * 512 * 512;
  const ushort_t* kB = kbf + (size_t)b * 512 * 512;
  const ushort_t* vB = vbf + (size_t)b * 512 * 512;
  float* oB = out + (size_t)b * SEQT * HDIM;

  ushort_t* Pw = Ps + w * 1024;  // 16 rows x 64 shorts, swizzled

#pragma unroll
  for (int half = 0; half < 2; ++half) {
    const int qt = half ? j : (255 - j);  // heavy tile first
    const int q0 = qt * 16;
    const int ktiles = (q0 + 79) >> 6;  // ceil((q0+16)/64)

    // Q A-fragments, pre-packed: group = qt.
    bf16x8 qf[2];
#pragma unroll
    for (int ks = 0; ks < 2; ++ks)
      qf[ks] = *(const bf16x8*)&qB[(size_t)(qt * 2 + ks) * 512 + lane * 8];

    f32x4 o[4];
    float lsum[4];
#pragma unroll
    for (int nt = 0; nt < 4; ++nt) o[nt] = (f32x4){0.f, 0.f, 0.f, 0.f};
#pragma unroll
    for (int i = 0; i < 4; ++i) lsum[i] = 0.f;

    for (int kt = w; kt < ktiles; kt += 8) {
      const int k0 = kt * 64;

      // S = Q K^T : 8 MFMAs, loads adjacent (short live ranges, no spill).
      f32x4 s[4];
#pragma unroll
      for (int nt = 0; nt < 4; ++nt) s[nt] = (f32x4){0.f, 0.f, 0.f, 0.f};
#pragma unroll
      for (int ks = 0; ks < 2; ++ks)
#pragma unroll
        for (int nt = 0; nt < 4; ++nt) {
          bf16x8 kf = *(const bf16x8*)&kB[(size_t)((kt * 4 + nt) * 2 + ks) * 512 +
                                          lane * 8];
          s[nt] = MFMA16(qf[ks], kf, s[nt]);
        }

      // Causal mask (diagonal tiles only).
      if (k0 + 63 > q0) {
        const int rbase = q0 + quad * 4;
#pragma unroll
        for (int nt = 0; nt < 4; ++nt) {
          const int col = k0 + nt * 16 + n;
#pragma unroll
          for (int i = 0; i < 4; ++i)
            if (col > rbase + i) s[nt][i] = NEG;
        }
      }

      // Max-free softmax: p = exp(s); lane-local l; swizzled P pack.
#pragma unroll
      for (int nt = 0; nt < 4; ++nt)
#pragma unroll
        for (int i = 0; i < 4; ++i) {
          const float p = __expf(s[nt][i]);
          lsum[i] += p;
          const int row = quad * 4 + i;
          Pw[row * 64 + (((2 * nt + (n >> 3)) ^ (row & 7)) * 8) + (n & 7)] =
              f2bf(p);
        }

      // P A-frags back (conflict-free b128); O += P V.
      bf16x8 pa0 = *(const bf16x8*)&Pw[n * 64 + ((quad ^ (n & 7)) * 8)];
      bf16x8 pa1 = *(const bf16x8*)&Pw[n * 64 + (((4 + quad) ^ (n & 7)) * 8)];
#pragma unroll
      for (int nt = 0; nt < 4; ++nt) {
        bf16x8 vf = *(const bf16x8*)&vB[(size_t)((kt * 4 + nt) * 2 + 0) * 512 +
                                        lane * 8];
        o[nt] = MFMA16(pa0, vf, o[nt]);
      }
#pragma unroll
      for (int nt = 0; nt < 4; ++nt) {
        bf16x8 vf = *(const bf16x8*)&vB[(size_t)((kt * 4 + nt) * 2 + 1) * 512 +
                                        lane * 8];
        o[nt] = MFMA16(pa1, vf, o[nt]);
      }
    }

    // Reduce lsum across the 16 n-lanes of each row.
#pragma unroll
    for (int off = 1; off < 16; off <<= 1)
#pragma unroll
      for (int i = 0; i < 4; ++i) lsum[i] += __shfl_xor(lsum[i], off);

    // ---- Additive merge of 8 waves for this tile. ----
    __syncthreads();  // all waves done with Ps (aliases Om)

    float* OmW = Om + w * 1088;  // 16 rows x 68 floats
#pragma unroll
    for (int nt = 0; nt < 4; ++nt)
#pragma unroll
      for (int i = 0; i < 4; ++i)
        OmW[(quad * 4 + i) * 68 + nt * 16 + n] = o[nt][i];
    if (n == 0)
#pragma unroll
      for (int i = 0; i < 4; ++i) Ol[w * 16 + quad * 4 + i] = lsum[i];
    __syncthreads();

    // Final combine: 512 threads x 2 floats (16 rows x 64 cols).
    {
      const int r = tid >> 5;          // 0..15
      const int c0 = (tid & 31) * 2;   // 0..62
      float a0 = 0.f, a1 = 0.f, ls = 0.f;
#pragma unroll
      for (int ww = 0; ww < 8; ++ww) {
        a0 += Om[ww * 1088 + r * 68 + c0];
        a1 += Om[ww * 1088 + r * 68 + c0 + 1];
        ls += Ol[ww * 16 + r];
      }
      const float inv = 1.0f / ls;
      *(float2*)&oB[(size_t)(q0 + r) * HDIM + c0] =
          make_float2(a0 * inv, a1 * inv);
    }
    __syncthreads();  // combine reads done before next half rewrites Ps
  }
}

extern "C" void kernel_launch(void* const* d_in, const int* in_sizes, int n_in,
                              void* d_out, int out_size, void* d_ws, size_t ws_size,
                              hipStream_t stream) {
  const float* x = (const float*)d_in[0];
  const float* Wq = (const float*)d_in[1];
  const float* Wk = (const float*)d_in[2];
  const float* Wv = (const float*)d_in[3];
  float* out = (float*)d_out;

  ushort_t* wtf = (ushort_t*)d_ws;
  ushort_t* qbf = wtf + 3 * 16 * 4 * 512;
  ushort_t* kbf = qbf + (size_t)BATCH * 512 * 512;
  ushort_t* vbf = kbf + (size_t)BATCH * 512 * 512;

  convert_w<<<48, 256, 0, stream>>>(Wq, Wk, Wv, wtf);
  qkv_proj<<<BATCH * SEQT / 16, 384, 0, stream>>>(x, wtf, qbf, kbf, vbf);
  attn<<<512, 512, 0, stream>>>(qbf, kbf, vbf, out);
}